// Round 9
// baseline (95.581 us; speedup 1.0000x reference)
//
#include <hip/hip_runtime.h>

// VQEmbedding: x [N=32768, D=256] fp32, embedding [M=1024, D=256] fp32.
// Outputs (flat fp32): quantized [N*D], loss [1], indices [N] (as float), perplexity [1].
// R9: 128 rows/block, 512 thr (8 waves), grid=256 (1 block/CU -> table staged ONCE per CU).
// Two 4-wave teams split M (A: embs 0-511, B: 512-1023); each wave holds 32 x-rows
// (cf=2) in split-f16 regs; 16-emb e-tiles (16KB) staged tile16-major via
// global_load_lds, double-buffered; per kk: 2 ds_read_b128 : 6 MFMA (latency
// self-hidden). Cross-team argmin merge in LDS (tie -> team A = lower idx).
// dist = ||e||^2 - 2 x.e ; loss = 1.25*(sum bestdist + ||x||_F^2)/(N*D).

constexpr int D = 256;
constexpr int M = 1024;
constexpr int ROWS = 128;   // x rows per block

typedef _Float16 f16;
typedef __attribute__((ext_vector_type(8))) _Float16 f16x8;
typedef __attribute__((ext_vector_type(4))) float f32x4;

// ws layout (bytes):
//   [0..4)        loss accumulator (float)
//   [4..4100)     counts (1024 floats, float-idx 1..1025)
//   [4112..8208)  enorm (1024 floats, float-idx 1028..2052)
//   [8320..1056896)  e split-f16 table, tile16-major:
//     16B element v (65536): lane=v&63, unit=v>>6; spl=unit&1, kk=(unit>>1)&7,
//     t16=unit>>4 (0..63); content = split(e[t16*16+(lane&15)][kk*32+(lane>>4)*8..+8]),
//     spl0=hi, spl1=lo.  One tile16 = 16KB contiguous.
constexpr size_t WS_ENORM_F = 1028;
constexpr size_t WS_TAB_B   = 8320;
constexpr size_t WS_NEEDED  = 1056896;

__device__ inline void gload_lds16(const void* g, void* l) {
    __builtin_amdgcn_global_load_lds(
        (const __attribute__((address_space(1))) unsigned int*)(g),
        (__attribute__((address_space(3))) unsigned int*)(l), 16, 0, 0);
}

// ---------------- prep: tile16-major split-f16 e table + exact ||e||^2 ----------------
__global__ __launch_bounds__(256) void prep_kernel(const float* __restrict__ e,
                                                   float* __restrict__ ws) {
    const int b = blockIdx.x, t = threadIdx.x;
    if (b < 256) {
        int v    = b * 256 + t;               // 16B element index
        int lane = v & 63, unit = v >> 6;
        int spl = unit & 1, kk = (unit >> 1) & 7, t16 = unit >> 4;
        int lr = lane & 15, q = lane >> 4;
        const float* p = e + (size_t)(t16 * 16 + lr) * D + kk * 32 + q * 8;
        f32x4 a = *reinterpret_cast<const f32x4*>(p);
        f32x4 c = *reinterpret_cast<const f32x4*>(p + 4);
        f16 h0=(f16)a.x,h1=(f16)a.y,h2=(f16)a.z,h3=(f16)a.w;
        f16 h4=(f16)c.x,h5=(f16)c.y,h6=(f16)c.z,h7=(f16)c.w;
        f16x8 out;
        if (spl == 0) out = (f16x8){h0,h1,h2,h3,h4,h5,h6,h7};
        else          out = (f16x8){(f16)(a.x-(float)h0),(f16)(a.y-(float)h1),
                                    (f16)(a.z-(float)h2),(f16)(a.w-(float)h3),
                                    (f16)(c.x-(float)h4),(f16)(c.y-(float)h5),
                                    (f16)(c.z-(float)h6),(f16)(c.w-(float)h7)};
        *reinterpret_cast<f16x8*>((char*)ws + WS_TAB_B + (size_t)v * 16) = out;
    } else {
        int row  = (b - 256) * 4 + (t >> 6);  // 1024 rows over blocks 256..511
        int lane = t & 63;
        f32x4 a = *reinterpret_cast<const f32x4*>(e + (size_t)row * D + lane * 4);
        float s = fmaf(a.x, a.x, fmaf(a.y, a.y, fmaf(a.z, a.z, a.w * a.w)));
#pragma unroll
        for (int o = 32; o > 0; o >>= 1) s += __shfl_down(s, o, 64);
        if (lane == 0) ws[WS_ENORM_F + row] = s;
    }
}

// ---------------- fused main kernel ----------------
__global__ __launch_bounds__(512, 2) void vq_fused_kernel(
    const float* __restrict__ x, const float* __restrict__ e,
    float* __restrict__ outQ, float* __restrict__ outIdx, float* __restrict__ ws)
{
    __shared__ ushort ebuf[2][2][8192];  // [buf][team][16KB tile16], lane-linear
    __shared__ float  en_s[M];           // 4 KB
    __shared__ float  mval[ROWS];
    __shared__ int    midx[ROWS];
    __shared__ int    fidx[ROWS];
    __shared__ float  lsum[8];

    const int tid  = threadIdx.x;
    const int w    = __builtin_amdgcn_readfirstlane(tid >> 6);  // wave id 0..7
    const int l    = tid & 63;
    const int lr   = l & 15, q = l >> 4;
    const int team = w >> 2;             // 0: embs 0-511, 1: embs 512-1023
    const int wr   = w & 3;              // row quarter within team
    const int R    = blockIdx.x * ROWS;
    const char* tab = (const char*)ws + WS_TAB_B;

    // staging: per gen, 32 segs of 1KB (2 tiles x 16); wave w stages segs w*4..w*4+3
    auto stage = [&](int buf, int g) {
#pragma unroll
        for (int i = 0; i < 4; ++i) {
            int S = w * 4 + i, tm = S >> 4, sg = S & 15;
            gload_lds16(tab + (size_t)(tm * 32 + g) * 16384 + sg * 1024 + l * 16,
                        &ebuf[buf][tm][sg * 512]);
        }
    };
    stage(0, 0);                         // tile gen 0 lands while we do the prologue

    // enorm -> LDS
    if (tid < 256) {
        f32x4 v = *reinterpret_cast<const f32x4*>(ws + WS_ENORM_F + tid * 4);
        *reinterpret_cast<f32x4*>(&en_s[tid * 4]) = v;
    }

    // x rows -> split-f16 regs: wave w owns rows R + wr*32 + cf*16 + lr (cf=0,1)
    f16x8 Xh[2][8], Xl[2][8];
    float xn[2];
#pragma unroll
    for (int cf = 0; cf < 2; ++cf) {
        float s = 0.f;
#pragma unroll
        for (int kk = 0; kk < 8; ++kk) {
            const float* p = x + (size_t)(R + wr * 32 + cf * 16 + lr) * D + kk * 32 + q * 8;
            f32x4 a = *reinterpret_cast<const f32x4*>(p);
            f32x4 c = *reinterpret_cast<const f32x4*>(p + 4);
            f16 h0=(f16)a.x,h1=(f16)a.y,h2=(f16)a.z,h3=(f16)a.w;
            f16 h4=(f16)c.x,h5=(f16)c.y,h6=(f16)c.z,h7=(f16)c.w;
            Xh[cf][kk] = (f16x8){h0,h1,h2,h3,h4,h5,h6,h7};
            Xl[cf][kk] = (f16x8){(f16)(a.x-(float)h0),(f16)(a.y-(float)h1),
                                 (f16)(a.z-(float)h2),(f16)(a.w-(float)h3),
                                 (f16)(c.x-(float)h4),(f16)(c.y-(float)h5),
                                 (f16)(c.z-(float)h6),(f16)(c.w-(float)h7)};
            s = fmaf(a.x,a.x,fmaf(a.y,a.y,fmaf(a.z,a.z,fmaf(a.w,a.w,
                fmaf(c.x,c.x,fmaf(c.y,c.y,fmaf(c.z,c.z,fmaf(c.w,c.w,s))))))));
        }
        s += __shfl_xor(s, 16, 64);      // sum 4 q-groups -> full ||x_row||^2
        s += __shfl_xor(s, 32, 64);
        xn[cf] = s;
    }
    __syncthreads();                     // gen 0 staged (vmcnt drained), en_s ready

    float bV[2] = {3.4e38f, 3.4e38f};
    int   bI[2] = {0, 0};

    for (int g = 0; g < 32; ++g) {       // 32 gens x 16 embs per team
        const ushort* eb = &ebuf[g & 1][team][0];
        if (g < 31) stage((g + 1) & 1, g + 1);

        f32x4 accA[2], accB[2];          // split chains per cf
#pragma unroll
        for (int cf = 0; cf < 2; ++cf) {
            accA[cf] = (f32x4){0.f,0.f,0.f,0.f};
            accB[cf] = (f32x4){0.f,0.f,0.f,0.f};
        }
        __builtin_amdgcn_s_setprio(1);
#pragma unroll
        for (int kk = 0; kk < 8; ++kk) { // 2 ds_read_b128 : 6 MFMA
            f16x8 Ah = *reinterpret_cast<const f16x8*>(eb + (kk*2+0)*512 + l*8);
            f16x8 Al = *reinterpret_cast<const f16x8*>(eb + (kk*2+1)*512 + l*8);
            accA[0] = __builtin_amdgcn_mfma_f32_16x16x32_f16(Ah, Xh[0][kk], accA[0], 0, 0, 0);
            accA[0] = __builtin_amdgcn_mfma_f32_16x16x32_f16(Ah, Xl[0][kk], accA[0], 0, 0, 0);
            accB[0] = __builtin_amdgcn_mfma_f32_16x16x32_f16(Al, Xh[0][kk], accB[0], 0, 0, 0);
            accA[1] = __builtin_amdgcn_mfma_f32_16x16x32_f16(Ah, Xh[1][kk], accA[1], 0, 0, 0);
            accA[1] = __builtin_amdgcn_mfma_f32_16x16x32_f16(Ah, Xl[1][kk], accA[1], 0, 0, 0);
            accB[1] = __builtin_amdgcn_mfma_f32_16x16x32_f16(Al, Xh[1][kk], accB[1], 0, 0, 0);
        }
        __builtin_amdgcn_s_setprio(0);
        __syncthreads();                 // all eb reads done + gen g+1 landed

        // fold: emb = team*512 + g*16 + q*4 + i (ascends with g,i -> strict < = first min)
        const int mbase = team * 512 + g * 16;
        f32x4 en4 = *reinterpret_cast<const f32x4*>(&en_s[mbase + q * 4]);
#pragma unroll
        for (int i = 0; i < 4; ++i) {
            int mi = mbase + q * 4 + i;
#pragma unroll
            for (int cf = 0; cf < 2; ++cf) {
                float dv = fmaf(-2.f, accA[cf][i] + accB[cf][i], en4[i]);
                if (dv < bV[cf]) { bV[cf] = dv; bI[cf] = mi; }
            }
        }
    }

    // reduce across q-groups (lanes sharing an x-row), tie -> lower idx
#pragma unroll
    for (int cf = 0; cf < 2; ++cf) {
#pragma unroll
        for (int mk = 16; mk <= 32; mk <<= 1) {
            float ov = __shfl_xor(bV[cf], mk, 64);
            int   oi = __shfl_xor(bI[cf], mk, 64);
            if (ov < bV[cf] || (ov == bV[cf] && oi < bI[cf])) { bV[cf] = ov; bI[cf] = oi; }
        }
    }
    // team A publishes candidates; team B merges (A idx always lower -> tie prefers A)
    if (team == 0 && q == 0) {
#pragma unroll
        for (int cf = 0; cf < 2; ++cf) {
            int r = wr * 32 + cf * 16 + lr;
            mval[r] = bV[cf]; midx[r] = bI[cf];
        }
    }
    __syncthreads();
    if (team == 1 && q == 0) {
        float ls = 0.f;
#pragma unroll
        for (int cf = 0; cf < 2; ++cf) {
            int r = wr * 32 + cf * 16 + lr;
            float av = mval[r]; int ai = midx[r];
            float fv; int fi;
            if (bV[cf] < av) { fv = bV[cf]; fi = bI[cf]; } else { fv = av; fi = ai; }
            fidx[r] = fi;
            outIdx[R + r] = (float)fi;
            atomicAdd(ws + 1 + fi, 1.0f);
            ls += fv + xn[cf];
        }
#pragma unroll
        for (int o = 8; o > 0; o >>= 1) ls += __shfl_down(ls, o, 16);
        if (lr == 0) lsum[w] = ls;
    }
    __syncthreads();
    if (tid == 0) atomicAdd(ws, lsum[4] + lsum[5] + lsum[6] + lsum[7]);

    // fused gather: quantized = embedding[idx] (exact fp32), nontemporal store
#pragma unroll
    for (int it = 0; it < 16; ++it) {
        int u = it * 512 + tid;
        int row = u >> 6, c4 = u & 63;   // 128 rows x 64 f32x4 units
        f32x4 v = *reinterpret_cast<const f32x4*>(e + (size_t)fidx[row] * D + c4 * 4);
        __builtin_nontemporal_store(v, reinterpret_cast<f32x4*>(outQ + (size_t)(R + row) * D + c4 * 4));
    }
}

// ---------------- fallback fp32 path (only if ws too small) ----------------
__global__ void enorm_kernel(const float* __restrict__ e, float* __restrict__ enorm) {
    int m = blockIdx.x, l = threadIdx.x;
    const f32x4 v = *reinterpret_cast<const f32x4*>(e + m * D + l * 4);
    float s = fmaf(v.x, v.x, fmaf(v.y, v.y, fmaf(v.z, v.z, v.w * v.w)));
#pragma unroll
    for (int o = 32; o > 0; o >>= 1) s += __shfl_down(s, o, 64);
    if (l == 0) enorm[m] = s;
}

__global__ __launch_bounds__(256, 2) void vq_main_kernel(
    const float* __restrict__ x, const float* __restrict__ e,
    float* __restrict__ outQ, float* __restrict__ outIdx, float* __restrict__ ws) {
    __shared__ f32x4 xs[64][64];
    __shared__ float cval[4][64];
    __shared__ int   cidx[4][64];
    __shared__ int   fidx[64];
    const int tid = threadIdx.x, row0 = blockIdx.x * 64;
#pragma unroll
    for (int it = 0; it < 16; ++it) {
        int f = it * 256 + tid, rr = f >> 6, c4 = f & 63;
        xs[rr][c4 ^ (rr & 7)] = *reinterpret_cast<const f32x4*>(x + (row0 + rr) * D + c4 * 4);
    }
    __syncthreads();
    const int r = tid & 63, c = __builtin_amdgcn_readfirstlane(tid >> 6), sw = r & 7;
    float xnorm = 0.f;
    if (c == 0) {
        f32x4 a = (f32x4){0.f,0.f,0.f,0.f};
        for (int d4 = 0; d4 < 64; ++d4) {
            f32x4 xv = xs[r][d4 ^ sw];
            a.x = fmaf(xv.x, xv.x, a.x); a.y = fmaf(xv.y, xv.y, a.y);
            a.z = fmaf(xv.z, xv.z, a.z); a.w = fmaf(xv.w, xv.w, a.w);
        }
        xnorm = (a.x + a.y) + (a.z + a.w);
    }
    const float* __restrict__ enorm = ws + WS_ENORM_F;
    float bestVal = 3.4e38f; int bestIdx = 0;
    for (int chunk = 0; chunk < M / 32; ++chunk) {
        const int m0 = chunk * 32 + c * 8;
        f32x4 acc[8];
#pragma unroll
        for (int mi = 0; mi < 8; ++mi) acc[mi] = (f32x4){0.f,0.f,0.f,0.f};
#pragma unroll 2
        for (int d4 = 0; d4 < 64; ++d4) {
            const f32x4 xv = xs[r][d4 ^ sw];
#pragma unroll
            for (int mi = 0; mi < 8; ++mi) {
                const f32x4 ev = *reinterpret_cast<const f32x4*>(e + (m0 + mi) * D + d4 * 4);
                acc[mi].x = fmaf(xv.x, ev.x, acc[mi].x); acc[mi].y = fmaf(xv.y, ev.y, acc[mi].y);
                acc[mi].z = fmaf(xv.z, ev.z, acc[mi].z); acc[mi].w = fmaf(xv.w, ev.w, acc[mi].w);
            }
        }
#pragma unroll
        for (int mi = 0; mi < 8; ++mi) {
            float dot = (acc[mi].x + acc[mi].y) + (acc[mi].z + acc[mi].w);
            float val = enorm[m0 + mi] - 2.0f * dot;
            if (val < bestVal) { bestVal = val; bestIdx = m0 + mi; }
        }
    }
    cval[c][r] = bestVal; cidx[c][r] = bestIdx;
    __syncthreads();
    if (c == 0) {
        float bv = bestVal; int bi = bestIdx;
#pragma unroll
        for (int cc = 1; cc < 4; ++cc) {
            float v = cval[cc][r]; int i = cidx[cc][r];
            if (v < bv || (v == bv && i < bi)) { bv = v; bi = i; }
        }
        fidx[r] = bi; outIdx[row0 + r] = (float)bi;
        atomicAdd(ws + 1 + bi, 1.0f);
        float dist = bv + xnorm;
#pragma unroll
        for (int o = 32; o > 0; o >>= 1) dist += __shfl_down(dist, o, 64);
        if (r == 0) atomicAdd(ws, dist);
    }
    __syncthreads();
#pragma unroll
    for (int it = 0; it < 16; ++it) {
        int f = it * 256 + tid, rr = f >> 6, c4 = f & 63;
        *reinterpret_cast<f32x4*>(outQ + (row0 + rr) * D + c4 * 4) =
            *reinterpret_cast<const f32x4*>(e + fidx[rr] * D + c4 * 4);
    }
}

// ---------------- finalize: loss + perplexity ----------------
__global__ void vq_final_kernel(const float* __restrict__ ws,
                                float* __restrict__ outLoss, float* __restrict__ outPpl,
                                float invN, float invND) {
    int t = threadIdx.x;
    float p = ws[1 + t] * invN;
    float term = p * logf(p + 1e-10f);
#pragma unroll
    for (int o = 32; o > 0; o >>= 1) term += __shfl_down(term, o, 64);
    __shared__ float s[16];
    if ((t & 63) == 0) s[t >> 6] = term;
    __syncthreads();
    if (t == 0) {
        float tot = 0.f;
#pragma unroll
        for (int i = 0; i < 16; ++i) tot += s[i];
        *outPpl  = expf(-tot);
        *outLoss = 1.25f * ws[0] * invND;
    }
}

extern "C" void kernel_launch(void* const* d_in, const int* in_sizes, int n_in,
                              void* d_out, int out_size, void* d_ws, size_t ws_size,
                              hipStream_t stream) {
    const float* x = (const float*)d_in[0];
    const float* e = (const float*)d_in[1];
    const int NX = in_sizes[0];     // N*D = 8388608
    const int N  = NX / D;          // 32768

    float* out     = (float*)d_out;
    float* outQ    = out;
    float* outLoss = out + NX;
    float* outIdx  = out + NX + 1;
    float* outPpl  = out + NX + 1 + N;
    float* ws      = (float*)d_ws;

    (void)hipMemsetAsync(d_ws, 0, 4100, stream);    // loss + counts
    if (ws_size >= WS_NEEDED && (N % ROWS) == 0) {
        prep_kernel<<<512, 256, 0, stream>>>(e, ws);
        vq_fused_kernel<<<N / ROWS, 512, 0, stream>>>(x, e, outQ, outIdx, ws);
    } else {
        enorm_kernel<<<M, 64, 0, stream>>>(e, ws + WS_ENORM_F);
        vq_main_kernel<<<N / 64, 256, 0, stream>>>(x, e, outQ, outIdx, ws);
    }
    vq_final_kernel<<<1, 1024, 0, stream>>>(ws, outLoss, outPpl,
                                            1.0f / (float)N, 1.0f / (float)NX);
}